// Round 18
// baseline (3505.317 us; speedup 1.0000x reference)
//
#include <hip/hip_runtime.h>
#include <math.h>

constexpr int DM   = 768;
constexpr int SEQL = 667;   // 1 + 1 + 392 + 77 + 196
constexpr int NB   = 8;
constexpr int NHEAD= 12;
constexpr int HDIM = 64;
constexpr int ROWS = NB * SEQL; // 5336
constexpr int FF   = 3072;

using u16   = unsigned short;
using bf16x8 = __attribute__((ext_vector_type(8))) short;
using f32x4  = __attribute__((ext_vector_type(4))) float;

// ---------------- static device buffers ----------------
__device__ __align__(16) float g_pos [(size_t)SEQL * DM];
__device__ __align__(16) float g_x   [(size_t)ROWS * DM];
__device__ __align__(16) u16   g_y   [(size_t)ROWS * DM];       // bf16: ln out / attn out
__device__ __align__(16) u16   g_qkvb[(size_t)ROWS * 3 * DM];   // bf16 fused q|k|v
__device__ __align__(16) u16   g_hid [(size_t)ROWS * FF];       // bf16 FFN hidden
__device__ __align__(16) u16   g_pobs[(size_t)NB * 392 * DM];
__device__ __align__(16) u16   g_pgoal[(size_t)NB * 196 * DM];
__device__ __align__(16) float g_ptok[(size_t)NB * DM];
__device__ __align__(16) float g_hbuf[(size_t)NB * DM];         // pose hidden
// transposed bf16 weights
__device__ __align__(16) u16   g_wqkvT[(size_t)12 * 3 * DM * DM]; // per layer: [2304][768]
__device__ __align__(16) u16   g_wpT  [(size_t)12 * DM * DM];
__device__ __align__(16) u16   g_w1T  [(size_t)12 * FF * DM];
__device__ __align__(16) u16   g_w2T  [(size_t)12 * DM * FF];
__device__ __align__(16) u16   g_obsT [(size_t)DM * DM];
__device__ __align__(16) u16   g_goalT[(size_t)DM * DM];

__device__ __forceinline__ u16 f2b(float x) {
  union { float f; unsigned u; } c{x};
  return (u16)((c.u + 0x7FFFu + ((c.u >> 16) & 1u)) >> 16);
}

// async global->LDS, 16B/lane; LDS dest must be WAVE-UNIFORM base (HW adds lane*16)
__device__ __forceinline__ void gload16(const u16* g, u16* l) {
  __builtin_amdgcn_global_load_lds(
      (const __attribute__((address_space(1))) void*)g,
      (__attribute__((address_space(3))) void*)l, 16, 0, 0);
}

// ---------------- block reduction (256 thr = 4 waves) ----------------
__device__ __forceinline__ float blk_sum256(float v, float* tmp) {
  #pragma unroll
  for (int o = 32; o; o >>= 1) v += __shfl_xor(v, o);
  int tid = threadIdx.x;
  if ((tid & 63) == 0) tmp[tid >> 6] = v;
  __syncthreads();
  float r = tmp[0] + tmp[1] + tmp[2] + tmp[3];
  __syncthreads();
  return r;
}

// ---------------- sincos positional embedding (f64 like reference) ----------
__global__ __launch_bounds__(256) void pos_kernel() {
  int t = blockIdx.x, tid = threadIdx.x;
  for (int i = 0; i < 3; i++) {
    int j = tid + i * 256;
    int je = j & ~1;
    double ang = (double)t / pow(10000.0, (double)je / 768.0);
    g_pos[(size_t)t * DM + j] = (j & 1) ? (float)cos(ang) : (float)sin(ang);
  }
}

// ---------------- patchify -> bf16 ----------------
__global__ __launch_bounds__(256) void patchify_stacked_kernel(const float* __restrict__ img) {
  int blk = blockIdx.x;
  int b = blk / 392, t = blk % 392;
  int s = t & 1, pp = t >> 1;
  int py = pp / 14, px = pp % 14;
  int tid = threadIdx.x;
  for (int i = 0; i < 3; i++) {
    int d = tid + i * 256;
    int c = d % 3, qd = d / 3;
    int pc = qd % 16, pr = qd / 16;
    size_t src = (((size_t)b * 224 + py * 16 + pr) * 224 + (px * 16 + pc)) * 6 + c * 2 + s;
    g_pobs[(size_t)blk * DM + d] = f2b(img[src]);
  }
}

__global__ __launch_bounds__(256) void patchify3_kernel(const float* __restrict__ img) {
  int blk = blockIdx.x;
  int b = blk / 196, t = blk % 196;
  int py = t / 14, px = t % 14;
  int tid = threadIdx.x;
  for (int i = 0; i < 3; i++) {
    int d = tid + i * 256;
    int c = d % 3, qd = d / 3;
    int pc = qd % 16, pr = qd / 16;
    size_t src = (((size_t)b * 224 + py * 16 + pr) * 224 + (px * 16 + pc)) * 3 + c;
    g_pgoal[(size_t)blk * DM + d] = f2b(img[src]);
  }
}

// ---------------- pose MLP (split: stage1 tiny, stage2 parallel GEMV) -------
__global__ __launch_bounds__(256) void pose1_kernel(
    const float* __restrict__ pose, const float* __restrict__ w1, const float* __restrict__ b1) {
  int b = blockIdx.x, tid = threadIdx.x;
  for (int i = 0; i < 3; i++) {
    int d = tid + i * 256;
    float s = b1[d];
    for (int j = 0; j < 7; j++) s += pose[b * 7 + j] * w1[j * DM + d];
    g_hbuf[b * DM + d] = fmaxf(s, 0.f);
  }
}

__global__ __launch_bounds__(256) void pose2_kernel(
    const float* __restrict__ w2, const float* __restrict__ b2) {
  __shared__ float hsh[DM];
  __shared__ float red[4][64];
  int b = blockIdx.x / 12, dg = blockIdx.x % 12;
  int tid = threadIdx.x;
  int dl = tid & 63, part = tid >> 6;
  for (int i = tid; i < DM; i += 256) hsh[i] = g_hbuf[b * DM + i];
  __syncthreads();
  int d = dg * 64 + dl;
  float s = 0.f;
  for (int j = part * 192; j < part * 192 + 192; j++) s += hsh[j] * w2[(size_t)j * DM + d];
  red[part][dl] = s;
  __syncthreads();
  if (part == 0)
    g_ptok[b * DM + d] = red[0][dl] + red[1][dl] + red[2][dl] + red[3][dl] + b2[d];
}

// ---------------- cls/pose/text token placement + pos add ---------------
__global__ __launch_bounds__(256) void embed_misc_kernel(
    const float* __restrict__ cls_tok, const float* __restrict__ tok_emb,
    const int* __restrict__ txt) {
  int blk = blockIdx.x;
  int b = blk / 79, r = blk % 79;
  int tid = threadIdx.x;
  for (int i = 0; i < 3; i++) {
    int d = tid + i * 256;
    float val; int tok;
    if (r == 0)      { tok = 0; val = cls_tok[d]; }
    else if (r == 1) { tok = 1; val = g_ptok[b * DM + d]; }
    else {
      int ii = r - 2; tok = 394 + ii;
      int tv = txt[b * 77 + ii];
      tv = tv < 0 ? 0 : (tv > 95 ? 95 : tv);
      val = tok_emb[(size_t)tv * DM + d];
    }
    g_x[((size_t)b * SEQL + tok) * DM + d] = val + g_pos[(size_t)tok * DM + d];
  }
}

// ---------------- LayerNorm: wave-per-row, 4 rows/block ----------------
__global__ __launch_bounds__(256) void ln_kernel(
    const float* __restrict__ g, const float* __restrict__ bta) {
  int row = blockIdx.x * 4 + (threadIdx.x >> 6);
  int l = threadIdx.x & 63;
  const float* xr = g_x + (size_t)row * DM;
  u16* yr        = g_y + (size_t)row * DM;
  float4 v[3];
  float s = 0.f;
  #pragma unroll
  for (int i = 0; i < 3; i++) {
    v[i] = *(const float4*)&xr[i * 256 + l * 4];
    s += v[i].x + v[i].y + v[i].z + v[i].w;
  }
  #pragma unroll
  for (int o = 32; o; o >>= 1) s += __shfl_xor(s, o);
  float mean = s * (1.f / 768.f);
  float vs = 0.f;
  #pragma unroll
  for (int i = 0; i < 3; i++) {
    float a = v[i].x - mean, b = v[i].y - mean, c = v[i].z - mean, d = v[i].w - mean;
    vs += a * a + b * b + c * c + d * d;
  }
  #pragma unroll
  for (int o = 32; o; o >>= 1) vs += __shfl_xor(vs, o);
  float rstd = rsqrtf(vs * (1.f / 768.f) + 1e-5f);
  #pragma unroll
  for (int i = 0; i < 3; i++) {
    int j = i * 256 + l * 4;
    const float4 gg = *(const float4*)&g[j];
    const float4 bb = *(const float4*)&bta[j];
    ushort4 o4;
    o4.x = f2b((v[i].x - mean) * rstd * gg.x + bb.x);
    o4.y = f2b((v[i].y - mean) * rstd * gg.y + bb.y);
    o4.z = f2b((v[i].z - mean) * rstd * gg.z + bb.z);
    o4.w = f2b((v[i].w - mean) * rstd * gg.w + bb.w);
    *(ushort4*)&yr[j] = o4;
  }
}

// ---------------- weight convert+transpose: W[K][N] f32 -> Wt[N][K] bf16 ----
__global__ __launch_bounds__(256) void convT_kernel(
    const float* __restrict__ W, u16* __restrict__ Wt,
    int K, int N, size_t istride, size_t ostride) {
  __shared__ float tile[32][33];
  int n0 = blockIdx.x * 32, k0 = blockIdx.y * 32;
  W  += (size_t)blockIdx.z * istride;
  Wt += (size_t)blockIdx.z * ostride;
  int tx = threadIdx.x & 31, tyb = threadIdx.x >> 5;
  for (int i = 0; i < 4; i++) {
    int kk = tyb + i * 8;
    tile[kk][tx] = W[(size_t)(k0 + kk) * N + n0 + tx];
  }
  __syncthreads();
  for (int i = 0; i < 4; i++) {
    int nn = tyb + i * 8;
    Wt[(size_t)(n0 + nn) * K + k0 + tx] = f2b(tile[tx][nn]);
  }
}

// ---------------- MFMA bf16 GEMM: C[M,N] = A[M,K] @ Bt[N,K]^T ----------------
// T3+T4: 3-buffer LDS pipeline, prefetch depth 2, COUNTED vmcnt + raw s_barrier
// (never vmcnt(0) in steady state). global_load_lds w=16, linear LDS dest,
// pre-swizzled global source (G21). BM=128, BN=64, BK=64. XCD-chunked swizzle.
// EPI 0: bf16 Cb = acc                  (QKV -> g_qkvb)
// EPI 1: f32 Cf = acc + bias + Cf       (proj / ff2 residual-accumulate)
// EPI 2: bf16 Cb = relu(acc + bias)     (ff1)
// EPI 3: f32 Cf(remap) = acc+bias+pos   (patch embeds)
template<int EPI>
__global__ __launch_bounds__(256) void gemm_bf16(
    const u16* __restrict__ A, const u16* __restrict__ Bt,
    const float* __restrict__ bias, float* Cf, u16* Cb,
    int M, int N, int K, int tpb, int tok_base) {
  __shared__ __align__(16) u16 Al[3][128 * 64];   // 48 KB
  __shared__ __align__(16) u16 Bl[3][64 * 64];    // 24 KB
  const int tid = threadIdx.x;

  // XCD-chunked bijective remap (m204)
  const int nwg = gridDim.x * gridDim.y;
  const int orig = blockIdx.y * gridDim.x + blockIdx.x;
  const int qq = nwg >> 3, rr2 = nwg & 7;
  const int xcd = orig & 7, choff = orig >> 3;
  const int wg = (xcd < rr2 ? xcd * (qq + 1) : rr2 * (qq + 1) + (xcd - rr2) * qq) + choff;
  const int m0 = (wg / gridDim.x) * 128;
  const int n0 = (wg % gridDim.x) * 64;

  const int w = tid >> 6, lane = tid & 63;
  const int wr = w >> 1, wc = w & 1;
  const int fr = lane & 15, kg = lane >> 4;

  // staging: lane covers row rowbase+(lane>>3), phys slot lane&7 (8 slots = 64 k).
  // Source is pre-swizzled: logical slot s = (lane&7) ^ ((row>>1)&7)  (G21).
  const int lrow = lane >> 3, lslot = lane & 7;
  unsigned asrc[4]; int aoff[4];
  #pragma unroll
  for (int g = 0; g < 4; g++) {
    int r = w * 32 + g * 8 + lrow;
    int s = lslot ^ ((r >> 1) & 7);
    int gr = m0 + r; if (gr >= M) gr = M - 1;
    asrc[g] = (unsigned)gr * (unsigned)K + s * 8;
    aoff[g] = (w * 32 + g * 8) * 64;          // wave-uniform LDS base (u16 elems)
  }
  unsigned bsrc[2]; int boff[2];
  #pragma unroll
  for (int g = 0; g < 2; g++) {
    int r = w * 16 + g * 8 + lrow;
    int s = lslot ^ ((r >> 1) & 7);
    bsrc[g] = (unsigned)(n0 + r) * (unsigned)K + s * 8;
    boff[g] = (w * 16 + g * 8) * 64;
  }

  f32x4 acc[4][2] = {};

#define STAGE(buf, k0)                                                  \
  do {                                                                  \
    _Pragma("unroll")                                                   \
    for (int g = 0; g < 4; g++)                                         \
      gload16(A + asrc[g] + (k0), &Al[buf][aoff[g]]);                   \
    _Pragma("unroll")                                                   \
    for (int g = 0; g < 2; g++)                                         \
      gload16(Bt + bsrc[g] + (k0), &Bl[buf][boff[g]]);                  \
  } while (0)

#define COMPUTE(buf, kk)                                                \
  do {                                                                  \
    bf16x8 af[4], bfr[2];                                               \
    _Pragma("unroll")                                                   \
    for (int i = 0; i < 4; i++) {                                       \
      int ar = wr * 64 + i * 16 + fr;                                   \
      int p = ((kk) * 4 + kg) ^ ((ar >> 1) & 7);                        \
      af[i] = *(const bf16x8*)&Al[buf][ar * 64 + p * 8];                \
    }                                                                   \
    _Pragma("unroll")                                                   \
    for (int j = 0; j < 2; j++) {                                       \
      int br = wc * 32 + j * 16 + fr;                                   \
      int p = ((kk) * 4 + kg) ^ ((br >> 1) & 7);                        \
      bfr[j] = *(const bf16x8*)&Bl[buf][br * 64 + p * 8];               \
    }                                                                   \
    _Pragma("unroll")                                                   \
    for (int i = 0; i < 4; i++)                                         \
      _Pragma("unroll")                                                 \
      for (int j = 0; j < 2; j++)                                       \
        acc[i][j] = __builtin_amdgcn_mfma_f32_16x16x32_bf16(            \
            af[i], bfr[j], acc[i][j], 0, 0, 0);                         \
  } while (0)

  // Pipeline: buffers hold tiles t, t+1, t+2. Counted vmcnt: each STAGE = 6
  // per-wave loads; waiting vmcnt(12) leaves (t+1,t+2) in flight, tile t done.
  const int NT = K >> 6;   // >= 12 for all our shapes
  STAGE(0, 0);
  STAGE(1, 64);
  int cb = 0;              // compute buffer
  for (int t = 0; t < NT - 2; ++t) {
    int sb = cb + 2; if (sb >= 3) sb -= 3;
    STAGE(sb, (t + 2) * 64);
    asm volatile("s_waitcnt vmcnt(12)" ::: "memory");
    __builtin_amdgcn_s_barrier();
    COMPUTE(cb, 0);
    COMPUTE(cb, 1);
    __builtin_amdgcn_s_barrier();   // readers done before buf[cb] is re-staged
    cb = cb + 1; if (cb >= 3) cb -= 3;
  }
  // t = NT-2: one stage (tile NT-1) still in flight
  asm volatile("s_waitcnt vmcnt(6)" ::: "memory");
  __builtin_amdgcn_s_barrier();
  COMPUTE(cb, 0);
  COMPUTE(cb, 1);
  __builtin_amdgcn_s_barrier();
  cb = cb + 1; if (cb >= 3) cb -= 3;
  // t = NT-1: drain fully
  asm volatile("s_waitcnt vmcnt(0)" ::: "memory");
  __builtin_amdgcn_s_barrier();
  COMPUTE(cb, 0);
  COMPUTE(cb, 1);
#undef STAGE
#undef COMPUTE

  // epilogue: C/D layout col = lane&15 (n), row = (lane>>4)*4 + r (m)
  #pragma unroll
  for (int i = 0; i < 4; i++) {
    #pragma unroll
    for (int j = 0; j < 2; j++) {
      int n = n0 + wc * 32 + j * 16 + fr;
      #pragma unroll
      for (int r = 0; r < 4; r++) {
        int m = m0 + wr * 64 + i * 16 + kg * 4 + r;
        if (m >= M) continue;
        float u = acc[i][j][r];
        if (EPI == 0) {
          Cb[(size_t)m * N + n] = f2b(u);
        } else if (EPI == 1) {
          u += bias[n];
          Cf[(size_t)m * N + n] += u;
        } else if (EPI == 2) {
          u = fmaxf(u + bias[n], 0.f);
          Cb[(size_t)m * N + n] = f2b(u);
        } else {
          int tok = tok_base + (m % tpb);
          size_t orow = (size_t)(m / tpb) * SEQL + tok;
          u += bias[n] + g_pos[(size_t)tok * DM + n];
          Cf[orow * DM + n] = u;
        }
      }
    }
  }
}

// ---------------- MFMA flash attention ----------------
__global__ __launch_bounds__(256) void attn_flash() {
  constexpr int KS = 3 * DM;
  constexpr float scale = 0.03608439182435161f; // 768^-0.5
  __shared__ __align__(16) u16 Kl[64 * 64];
  __shared__ __align__(16) u16 Vt[64 * 64];
  const int tid = threadIdx.x;
  const int w = tid >> 6, lane = tid & 63;
  const int fr = lane & 15, kg = lane >> 4;
  const int qt = blockIdx.x, h = blockIdx.y, b = blockIdx.z;
  const int q0 = qt * 64 + w * 16;
  const size_t bbase = (size_t)b * SEQL * KS + h * HDIM;

  int qr = q0 + fr; if (qr >= SEQL) qr = SEQL - 1;
  const size_t qrow = bbase + (size_t)qr * KS;
  const bf16x8 bq0 = *(const bf16x8*)&g_qkvb[qrow + kg * 8];
  const bf16x8 bq1 = *(const bf16x8*)&g_qkvb[qrow + 32 + kg * 8];

  f32x4 oacc[4] = {};
  float m_run = -3e38f, l_run = 0.f;

  for (int kv0 = 0; kv0 < SEQL; kv0 += 64) {
    __syncthreads();
    { // stage K [64 keys][8 slots], phys = slot ^ ((row>>1)&7)
      int row = tid >> 2, s0 = tid & 3;
      int krow = kv0 + row; if (krow >= SEQL) krow = SEQL - 1;
      const size_t gk = bbase + DM + (size_t)krow * KS;
      int sw = (row >> 1) & 7;
      *(bf16x8*)&Kl[row * 64 + (s0 ^ sw) * 8]       = *(const bf16x8*)&g_qkvb[gk + s0 * 8];
      *(bf16x8*)&Kl[row * 64 + ((s0 + 4) ^ sw) * 8] = *(const bf16x8*)&g_qkvb[gk + (s0 + 4) * 8];
    }
    { // stage V^T [64 d][8 key-slots], phys = slot ^ ((d>>1)&7)
      int d0 = (tid & 15) * 4;
      #pragma unroll
      for (int kk = 0; kk < 4; kk++) {
        int kl = (tid >> 4) + kk * 16;
        int krow = kv0 + kl; if (krow >= SEQL) krow = SEQL - 1;
        ushort4 v4 = *(const ushort4*)&g_qkvb[bbase + 2 * DM + (size_t)krow * KS + d0];
        int slot = kl >> 3, e = kl & 7;
        u16 vv[4] = {v4.x, v4.y, v4.z, v4.w};
        #pragma unroll
        for (int i = 0; i < 4; i++) {
          int d = d0 + i;
          Vt[d * 64 + ((slot ^ ((d >> 1) & 7)) * 8) + e] = vv[i];
        }
      }
    }
    __syncthreads();

    f32x4 sacc[4] = {};
    #pragma unroll
    for (int f = 0; f < 4; f++) {
      int row = f * 16 + fr;
      int sw = (row >> 1) & 7;
      bf16x8 ka0 = *(const bf16x8*)&Kl[row * 64 + ((kg ^ sw) * 8)];
      bf16x8 ka1 = *(const bf16x8*)&Kl[row * 64 + (((kg + 4) ^ sw) * 8)];
      sacc[f] = __builtin_amdgcn_mfma_f32_16x16x32_bf16(ka0, bq0, sacc[f], 0, 0, 0);
      sacc[f] = __builtin_amdgcn_mfma_f32_16x16x32_bf16(ka1, bq1, sacc[f], 0, 0, 0);
    }

    float p[4][4];
    float tmax = -3e38f;
    #pragma unroll
    for (int f = 0; f < 4; f++) {
      int keyb = kv0 + f * 16 + kg * 4;
      #pragma unroll
      for (int r = 0; r < 4; r++) {
        float sv = (keyb + r < SEQL) ? sacc[f][r] * scale : -3e38f;
        p[f][r] = sv;
        tmax = fmaxf(tmax, sv);
      }
    }
    tmax = fmaxf(tmax, __shfl_xor(tmax, 16));
    tmax = fmaxf(tmax, __shfl_xor(tmax, 32));
    float m_new = fmaxf(m_run, tmax);
    float alpha = __expf(m_run - m_new);
    m_run = m_new;

    float lsum = 0.f;
    #pragma unroll
    for (int f = 0; f < 4; f++)
      #pragma unroll
      for (int r = 0; r < 4; r++) {
        float e = __expf(p[f][r] - m_new);
        p[f][r] = e;
        lsum += e;
      }
    lsum += __shfl_xor(lsum, 16);
    lsum += __shfl_xor(lsum, 32);
    l_run = l_run * alpha + lsum;

    #pragma unroll
    for (int r = 0; r < 4; r++) {
      float aq = __shfl(alpha, kg * 4 + r);
      #pragma unroll
      for (int dg = 0; dg < 4; dg++) oacc[dg][r] *= aq;
    }

    unsigned pk_[4][2];
    #pragma unroll
    for (int f = 0; f < 4; f++)
      #pragma unroll
      for (int rr = 0; rr < 2; rr++)
        pk_[f][rr] = (unsigned)f2b(p[f][2 * rr]) | ((unsigned)f2b(p[f][2 * rr + 1]) << 16);

    bf16x8 pa[2];
    const int srcA = fr + 16 * (2 * (kg & 1));
    const int srcB = srcA + 16;
    const bool fsel = (kg >> 1) != 0;
    #pragma unroll
    for (int s = 0; s < 2; s++) {
      unsigned w0a = __shfl(pk_[2 * s][0], srcA), w0b = __shfl(pk_[2 * s + 1][0], srcA);
      unsigned w1a = __shfl(pk_[2 * s][1], srcA), w1b = __shfl(pk_[2 * s + 1][1], srcA);
      unsigned w2a = __shfl(pk_[2 * s][0], srcB), w2b = __shfl(pk_[2 * s + 1][0], srcB);
      unsigned w3a = __shfl(pk_[2 * s][1], srcB), w3b = __shfl(pk_[2 * s + 1][1], srcB);
      union { unsigned u[4]; bf16x8 v; } cvt;
      cvt.u[0] = fsel ? w0b : w0a;
      cvt.u[1] = fsel ? w1b : w1a;
      cvt.u[2] = fsel ? w2b : w2a;
      cvt.u[3] = fsel ? w3b : w3a;
      pa[s] = cvt.v;
    }

    #pragma unroll
    for (int dg = 0; dg < 4; dg++) {
      int row = dg * 16 + fr;
      int sw = (row >> 1) & 7;
      bf16x8 bv0 = *(const bf16x8*)&Vt[row * 64 + ((kg ^ sw) * 8)];
      bf16x8 bv1 = *(const bf16x8*)&Vt[row * 64 + (((kg + 4) ^ sw) * 8)];
      oacc[dg] = __builtin_amdgcn_mfma_f32_16x16x32_bf16(pa[0], bv0, oacc[dg], 0, 0, 0);
      oacc[dg] = __builtin_amdgcn_mfma_f32_16x16x32_bf16(pa[1], bv1, oacc[dg], 0, 0, 0);
    }
  }

  float inv = 1.f / l_run;
  #pragma unroll
  for (int r = 0; r < 4; r++) {
    float iq = __shfl(inv, kg * 4 + r);
    int q = q0 + kg * 4 + r;
    if (q >= SEQL) continue;
    size_t orow = ((size_t)b * SEQL + q) * DM + h * HDIM;
    #pragma unroll
    for (int dg = 0; dg < 4; dg++)
      g_y[orow + dg * 16 + fr] = f2b(oacc[dg][r] * iq);
  }
}

// ---------------- final: LN(lnf) -> cls -> LN(hln) -> head (f32 out) --------
__global__ __launch_bounds__(256) void final_kernel(
    const float* __restrict__ lnf_g, const float* __restrict__ lnf_b,
    const float* __restrict__ hln_g, const float* __restrict__ hln_b,
    const float* __restrict__ head_w, const float* __restrict__ head_b,
    float* __restrict__ out) {
  __shared__ float tmp[4];
  __shared__ float red[4][7];
  int b = blockIdx.x, tid = threadIdx.x;
  const float* xr = g_x + (size_t)b * SEQL * DM;
  float v0[3];
  float s = 0.f;
  for (int i = 0; i < 3; i++) { v0[i] = xr[tid + i * 256]; s += v0[i]; }
  float mean = blk_sum256(s, tmp) * (1.f / 768.f);
  float vs = 0.f;
  for (int i = 0; i < 3; i++) { float dd = v0[i] - mean; vs += dd * dd; }
  float var = blk_sum256(vs, tmp) * (1.f / 768.f);
  float rstd = rsqrtf(var + 1e-5f);
  float t1v[3];
  s = 0.f;
  for (int i = 0; i < 3; i++) {
    int d = tid + i * 256;
    t1v[i] = (v0[i] - mean) * rstd * lnf_g[d] + lnf_b[d];
    s += t1v[i];
  }
  float mean2 = blk_sum256(s, tmp) * (1.f / 768.f);
  vs = 0.f;
  for (int i = 0; i < 3; i++) { float dd = t1v[i] - mean2; vs += dd * dd; }
  float var2 = blk_sum256(vs, tmp) * (1.f / 768.f);
  float rstd2 = rsqrtf(var2 + 1e-5f);
  float po[7] = {};
  for (int i = 0; i < 3; i++) {
    int d = tid + i * 256;
    float t2 = (t1v[i] - mean2) * rstd2 * hln_g[d] + hln_b[d];
    for (int oo = 0; oo < 7; oo++) po[oo] += t2 * head_w[d * 7 + oo];
  }
  #pragma unroll
  for (int oo = 0; oo < 7; oo++) {
    #pragma unroll
    for (int off = 32; off; off >>= 1) po[oo] += __shfl_xor(po[oo], off);
  }
  if ((tid & 63) == 0) {
    int ww = tid >> 6;
    for (int oo = 0; oo < 7; oo++) red[ww][oo] = po[oo];
  }
  __syncthreads();
  if (tid < 7)
    out[b * 7 + tid] = red[0][tid] + red[1][tid] + red[2][tid] + red[3][tid] + head_b[tid];
}

// ---------------- host launch ----------------
extern "C" void kernel_launch(void* const* d_in, const int* in_sizes, int n_in,
                              void* d_out, int out_size, void* d_ws, size_t ws_size,
                              hipStream_t stream) {
  const float* images    = (const float*)d_in[0];
  const float* goal_imgs = (const float*)d_in[1];
  const float* pose      = (const float*)d_in[2];
  const int*   goals_txt = (const int*)  d_in[3];
  const float* obs_w     = (const float*)d_in[4];
  const float* obs_b     = (const float*)d_in[5];
  const float* goal_w    = (const float*)d_in[6];
  const float* goal_b    = (const float*)d_in[7];
  const float* tok_emb   = (const float*)d_in[8];
  const float* pose_w1   = (const float*)d_in[9];
  const float* pose_b1   = (const float*)d_in[10];
  const float* pose_w2   = (const float*)d_in[11];
  const float* pose_b2   = (const float*)d_in[12];
  const float* cls_tok   = (const float*)d_in[13];
  const float* wq        = (const float*)d_in[14];
  const float* wk        = (const float*)d_in[15];
  const float* wv        = (const float*)d_in[16];
  const float* proj_w    = (const float*)d_in[17];
  const float* proj_b    = (const float*)d_in[18];
  const float* ln1_g     = (const float*)d_in[19];
  const float* ln1_b     = (const float*)d_in[20];
  const float* ln2_g     = (const float*)d_in[21];
  const float* ln2_b     = (const float*)d_in[22];
  const float* ff_w1     = (const float*)d_in[23];
  const float* ff_b1     = (const float*)d_in[24];
  const float* ff_w2     = (const float*)d_in[25];
  const float* ff_b2     = (const float*)d_in[26];
  const float* lnf_g     = (const float*)d_in[27];
  const float* lnf_b     = (const float*)d_in[28];
  const float* hln_g     = (const float*)d_in[29];
  const float* hln_b     = (const float*)d_in[30];
  const float* head_w    = (const float*)d_in[31];
  const float* head_b    = (const float*)d_in[32];
  (void)d_ws; (void)ws_size; (void)in_sizes; (void)n_in; (void)out_size;

  u16* wqkvT; u16* wpT; u16* w1T; u16* w2T; u16* obsT; u16* goalT;
  hipGetSymbolAddress((void**)&wqkvT, HIP_SYMBOL(g_wqkvT));
  hipGetSymbolAddress((void**)&wpT,   HIP_SYMBOL(g_wpT));
  hipGetSymbolAddress((void**)&w1T,   HIP_SYMBOL(g_w1T));
  hipGetSymbolAddress((void**)&w2T,   HIP_SYMBOL(g_w2T));
  hipGetSymbolAddress((void**)&obsT,  HIP_SYMBOL(g_obsT));
  hipGetSymbolAddress((void**)&goalT, HIP_SYMBOL(g_goalT));
  u16* qkvb; u16* yb; u16* hid; u16* pobs; u16* pgoal; float* xb;
  hipGetSymbolAddress((void**)&qkvb, HIP_SYMBOL(g_qkvb));
  hipGetSymbolAddress((void**)&yb,   HIP_SYMBOL(g_y));
  hipGetSymbolAddress((void**)&hid,  HIP_SYMBOL(g_hid));
  hipGetSymbolAddress((void**)&pobs, HIP_SYMBOL(g_pobs));
  hipGetSymbolAddress((void**)&pgoal,HIP_SYMBOL(g_pgoal));
  hipGetSymbolAddress((void**)&xb,   HIP_SYMBOL(g_x));

  const size_t WS = (size_t)DM * DM;
  const size_t FS = (size_t)DM * FF;

  // weight convert+transpose
  convT_kernel<<<dim3(24, 24, 12), 256, 0, stream>>>(wq,     wqkvT,          DM, DM, WS, 3 * WS);
  convT_kernel<<<dim3(24, 24, 12), 256, 0, stream>>>(wk,     wqkvT + WS,     DM, DM, WS, 3 * WS);
  convT_kernel<<<dim3(24, 24, 12), 256, 0, stream>>>(wv,     wqkvT + 2 * WS, DM, DM, WS, 3 * WS);
  convT_kernel<<<dim3(24, 24, 12), 256, 0, stream>>>(proj_w, wpT,            DM, DM, WS, WS);
  convT_kernel<<<dim3(96, 24, 12), 256, 0, stream>>>(ff_w1,  w1T,            DM, FF, FS, FS);
  convT_kernel<<<dim3(24, 96, 12), 256, 0, stream>>>(ff_w2,  w2T,            FF, DM, FS, FS);
  convT_kernel<<<dim3(24, 24, 1),  256, 0, stream>>>(obs_w,  obsT,           DM, DM, 0, 0);
  convT_kernel<<<dim3(24, 24, 1),  256, 0, stream>>>(goal_w, goalT,          DM, DM, 0, 0);

  pos_kernel<<<SEQL, 256, 0, stream>>>();
  patchify_stacked_kernel<<<NB * 392, 256, 0, stream>>>(images);
  patchify3_kernel<<<NB * 196, 256, 0, stream>>>(goal_imgs);
  pose1_kernel<<<NB, 256, 0, stream>>>(pose, pose_w1, pose_b1);
  pose2_kernel<<<NB * 12, 256, 0, stream>>>(pose_w2, pose_b2);
  embed_misc_kernel<<<NB * 79, 256, 0, stream>>>(cls_tok, tok_emb, goals_txt);

  gemm_bf16<3><<<dim3(12, 25), 256, 0, stream>>>(
      pobs, obsT, obs_b, xb, nullptr, NB * 392, DM, DM, 392, 2);
  gemm_bf16<3><<<dim3(12, 13), 256, 0, stream>>>(
      pgoal, goalT, goal_b, xb, nullptr, NB * 196, DM, DM, 196, 471);

  for (int l = 0; l < 12; l++) {
    ln_kernel<<<ROWS / 4, 256, 0, stream>>>(ln1_g + l * DM, ln1_b + l * DM);
    gemm_bf16<0><<<dim3(36, 42), 256, 0, stream>>>(
        yb, wqkvT + (size_t)l * 3 * WS, nullptr, nullptr, qkvb, ROWS, 3 * DM, DM, 0, 0);
    attn_flash<<<dim3(11, NHEAD, NB), 256, 0, stream>>>();
    gemm_bf16<1><<<dim3(12, 42), 256, 0, stream>>>(
        yb, wpT + (size_t)l * WS, proj_b + l * DM, xb, nullptr, ROWS, DM, DM, 0, 0);
    ln_kernel<<<ROWS / 4, 256, 0, stream>>>(ln2_g + l * DM, ln2_b + l * DM);
    gemm_bf16<2><<<dim3(48, 42), 256, 0, stream>>>(
        yb, w1T + (size_t)l * FS, ff_b1 + l * FF, nullptr, hid, ROWS, FF, DM, 0, 0);
    gemm_bf16<1><<<dim3(12, 42), 256, 0, stream>>>(
        hid, w2T + (size_t)l * FS, ff_b2 + l * DM, xb, nullptr, ROWS, DM, FF, 0, 0);
  }

  final_kernel<<<NB, 256, 0, stream>>>(lnf_g, lnf_b, hln_g, hln_b, head_w, head_b,
                                       (float*)d_out);
}

// Round 19
// 3086.531 us; speedup vs baseline: 1.1357x; 1.1357x over previous
//
#include <hip/hip_runtime.h>
#include <math.h>

constexpr int DM   = 768;
constexpr int SEQL = 667;   // 1 + 1 + 392 + 77 + 196
constexpr int NB   = 8;
constexpr int NHEAD= 12;
constexpr int HDIM = 64;
constexpr int ROWS = NB * SEQL; // 5336
constexpr int FF   = 3072;

using u16   = unsigned short;
using bf16x8 = __attribute__((ext_vector_type(8))) short;
using f32x4  = __attribute__((ext_vector_type(4))) float;

// ---------------- static device buffers ----------------
__device__ __align__(16) float g_pos [(size_t)SEQL * DM];
__device__ __align__(16) float g_x   [(size_t)ROWS * DM];
__device__ __align__(16) u16   g_y   [(size_t)ROWS * DM];       // bf16: ln out / attn out
__device__ __align__(16) u16   g_qkvb[(size_t)ROWS * 3 * DM];   // bf16 fused q|k|v
__device__ __align__(16) u16   g_hid [(size_t)ROWS * FF];       // bf16 FFN hidden
__device__ __align__(16) u16   g_pobs[(size_t)NB * 392 * DM];
__device__ __align__(16) u16   g_pgoal[(size_t)NB * 196 * DM];
__device__ __align__(16) float g_ptok[(size_t)NB * DM];
__device__ __align__(16) float g_hbuf[(size_t)NB * DM];         // pose hidden
// transposed bf16 weights
__device__ __align__(16) u16   g_wqkvT[(size_t)12 * 3 * DM * DM]; // per layer: [2304][768]
__device__ __align__(16) u16   g_wpT  [(size_t)12 * DM * DM];
__device__ __align__(16) u16   g_w1T  [(size_t)12 * FF * DM];
__device__ __align__(16) u16   g_w2T  [(size_t)12 * DM * FF];
__device__ __align__(16) u16   g_obsT [(size_t)DM * DM];
__device__ __align__(16) u16   g_goalT[(size_t)DM * DM];

__device__ __forceinline__ u16 f2b(float x) {
  union { float f; unsigned u; } c{x};
  return (u16)((c.u + 0x7FFFu + ((c.u >> 16) & 1u)) >> 16);
}

// async global->LDS, 16B/lane; LDS dest must be WAVE-UNIFORM base (HW adds lane*16)
__device__ __forceinline__ void gload16(const u16* g, u16* l) {
  __builtin_amdgcn_global_load_lds(
      (const __attribute__((address_space(1))) void*)g,
      (__attribute__((address_space(3))) void*)l, 16, 0, 0);
}

// ---------------- block reduction (256 thr = 4 waves) ----------------
__device__ __forceinline__ float blk_sum256(float v, float* tmp) {
  #pragma unroll
  for (int o = 32; o; o >>= 1) v += __shfl_xor(v, o);
  int tid = threadIdx.x;
  if ((tid & 63) == 0) tmp[tid >> 6] = v;
  __syncthreads();
  float r = tmp[0] + tmp[1] + tmp[2] + tmp[3];
  __syncthreads();
  return r;
}

// ---------------- sincos positional embedding (f64 like reference) ----------
__global__ __launch_bounds__(256) void pos_kernel() {
  int t = blockIdx.x, tid = threadIdx.x;
  for (int i = 0; i < 3; i++) {
    int j = tid + i * 256;
    int je = j & ~1;
    double ang = (double)t / pow(10000.0, (double)je / 768.0);
    g_pos[(size_t)t * DM + j] = (j & 1) ? (float)cos(ang) : (float)sin(ang);
  }
}

// ---------------- patchify -> bf16 ----------------
__global__ __launch_bounds__(256) void patchify_stacked_kernel(const float* __restrict__ img) {
  int blk = blockIdx.x;
  int b = blk / 392, t = blk % 392;
  int s = t & 1, pp = t >> 1;
  int py = pp / 14, px = pp % 14;
  int tid = threadIdx.x;
  for (int i = 0; i < 3; i++) {
    int d = tid + i * 256;
    int c = d % 3, qd = d / 3;
    int pc = qd % 16, pr = qd / 16;
    size_t src = (((size_t)b * 224 + py * 16 + pr) * 224 + (px * 16 + pc)) * 6 + c * 2 + s;
    g_pobs[(size_t)blk * DM + d] = f2b(img[src]);
  }
}

__global__ __launch_bounds__(256) void patchify3_kernel(const float* __restrict__ img) {
  int blk = blockIdx.x;
  int b = blk / 196, t = blk % 196;
  int py = t / 14, px = t % 14;
  int tid = threadIdx.x;
  for (int i = 0; i < 3; i++) {
    int d = tid + i * 256;
    int c = d % 3, qd = d / 3;
    int pc = qd % 16, pr = qd / 16;
    size_t src = (((size_t)b * 224 + py * 16 + pr) * 224 + (px * 16 + pc)) * 3 + c;
    g_pgoal[(size_t)blk * DM + d] = f2b(img[src]);
  }
}

// ---------------- pose MLP (split: stage1 tiny, stage2 parallel GEMV) -------
__global__ __launch_bounds__(256) void pose1_kernel(
    const float* __restrict__ pose, const float* __restrict__ w1, const float* __restrict__ b1) {
  int b = blockIdx.x, tid = threadIdx.x;
  for (int i = 0; i < 3; i++) {
    int d = tid + i * 256;
    float s = b1[d];
    for (int j = 0; j < 7; j++) s += pose[b * 7 + j] * w1[j * DM + d];
    g_hbuf[b * DM + d] = fmaxf(s, 0.f);
  }
}

__global__ __launch_bounds__(256) void pose2_kernel(
    const float* __restrict__ w2, const float* __restrict__ b2) {
  __shared__ float hsh[DM];
  __shared__ float red[4][64];
  int b = blockIdx.x / 12, dg = blockIdx.x % 12;
  int tid = threadIdx.x;
  int dl = tid & 63, part = tid >> 6;
  for (int i = tid; i < DM; i += 256) hsh[i] = g_hbuf[b * DM + i];
  __syncthreads();
  int d = dg * 64 + dl;
  float s = 0.f;
  for (int j = part * 192; j < part * 192 + 192; j++) s += hsh[j] * w2[(size_t)j * DM + d];
  red[part][dl] = s;
  __syncthreads();
  if (part == 0)
    g_ptok[b * DM + d] = red[0][dl] + red[1][dl] + red[2][dl] + red[3][dl] + b2[d];
}

// ---------------- cls/pose/text token placement + pos add ---------------
__global__ __launch_bounds__(256) void embed_misc_kernel(
    const float* __restrict__ cls_tok, const float* __restrict__ tok_emb,
    const int* __restrict__ txt) {
  int blk = blockIdx.x;
  int b = blk / 79, r = blk % 79;
  int tid = threadIdx.x;
  for (int i = 0; i < 3; i++) {
    int d = tid + i * 256;
    float val; int tok;
    if (r == 0)      { tok = 0; val = cls_tok[d]; }
    else if (r == 1) { tok = 1; val = g_ptok[b * DM + d]; }
    else {
      int ii = r - 2; tok = 394 + ii;
      int tv = txt[b * 77 + ii];
      tv = tv < 0 ? 0 : (tv > 95 ? 95 : tv);
      val = tok_emb[(size_t)tv * DM + d];
    }
    g_x[((size_t)b * SEQL + tok) * DM + d] = val + g_pos[(size_t)tok * DM + d];
  }
}

// ---------------- LayerNorm: wave-per-row, 4 rows/block ----------------
__global__ __launch_bounds__(256) void ln_kernel(
    const float* __restrict__ g, const float* __restrict__ bta) {
  int row = blockIdx.x * 4 + (threadIdx.x >> 6);
  int l = threadIdx.x & 63;
  const float* xr = g_x + (size_t)row * DM;
  u16* yr        = g_y + (size_t)row * DM;
  float4 v[3];
  float s = 0.f;
  #pragma unroll
  for (int i = 0; i < 3; i++) {
    v[i] = *(const float4*)&xr[i * 256 + l * 4];
    s += v[i].x + v[i].y + v[i].z + v[i].w;
  }
  #pragma unroll
  for (int o = 32; o; o >>= 1) s += __shfl_xor(s, o);
  float mean = s * (1.f / 768.f);
  float vs = 0.f;
  #pragma unroll
  for (int i = 0; i < 3; i++) {
    float a = v[i].x - mean, b = v[i].y - mean, c = v[i].z - mean, d = v[i].w - mean;
    vs += a * a + b * b + c * c + d * d;
  }
  #pragma unroll
  for (int o = 32; o; o >>= 1) vs += __shfl_xor(vs, o);
  float rstd = rsqrtf(vs * (1.f / 768.f) + 1e-5f);
  #pragma unroll
  for (int i = 0; i < 3; i++) {
    int j = i * 256 + l * 4;
    const float4 gg = *(const float4*)&g[j];
    const float4 bb = *(const float4*)&bta[j];
    ushort4 o4;
    o4.x = f2b((v[i].x - mean) * rstd * gg.x + bb.x);
    o4.y = f2b((v[i].y - mean) * rstd * gg.y + bb.y);
    o4.z = f2b((v[i].z - mean) * rstd * gg.z + bb.z);
    o4.w = f2b((v[i].w - mean) * rstd * gg.w + bb.w);
    *(ushort4*)&yr[j] = o4;
  }
}

// ---------------- weight convert+transpose: W[K][N] f32 -> Wt[N][K] bf16 ----
__global__ __launch_bounds__(256) void convT_kernel(
    const float* __restrict__ W, u16* __restrict__ Wt,
    int K, int N, size_t istride, size_t ostride) {
  __shared__ float tile[32][33];
  int n0 = blockIdx.x * 32, k0 = blockIdx.y * 32;
  W  += (size_t)blockIdx.z * istride;
  Wt += (size_t)blockIdx.z * ostride;
  int tx = threadIdx.x & 31, tyb = threadIdx.x >> 5;
  for (int i = 0; i < 4; i++) {
    int kk = tyb + i * 8;
    tile[kk][tx] = W[(size_t)(k0 + kk) * N + n0 + tx];
  }
  __syncthreads();
  for (int i = 0; i < 4; i++) {
    int nn = tyb + i * 8;
    Wt[(size_t)(n0 + nn) * K + k0 + tx] = f2b(tile[tx][nn]);
  }
}

// ---------------- MFMA bf16 GEMM: C[M,N] = A[M,K] @ Bt[N,K]^T ----------------
// R17 2-phase dbuf structure, but 512 threads (8 waves, wave tile 32x32):
// same 128x64 block tile (FETCH unchanged), 2x waves/SIMD for latency hiding.
// global_load_lds w=16, linear LDS dest, pre-swizzled source (G21).
// EPI 0: bf16 Cb = acc                  (QKV -> g_qkvb)
// EPI 1: f32 Cf = acc + bias + Cf       (proj / ff2 residual-accumulate)
// EPI 2: bf16 Cb = relu(acc + bias)     (ff1)
// EPI 3: f32 Cf(remap) = acc+bias+pos   (patch embeds)
template<int EPI>
__global__ __launch_bounds__(512) void gemm_bf16(
    const u16* __restrict__ A, const u16* __restrict__ Bt,
    const float* __restrict__ bias, float* Cf, u16* Cb,
    int M, int N, int K, int tpb, int tok_base) {
  __shared__ __align__(16) u16 Al[2][128 * 64];   // 32 KB
  __shared__ __align__(16) u16 Bl[2][64 * 64];    // 16 KB
  const int tid = threadIdx.x;

  // XCD-chunked bijective remap (m204)
  const int nwg = gridDim.x * gridDim.y;
  const int orig = blockIdx.y * gridDim.x + blockIdx.x;
  const int qq = nwg >> 3, rr2 = nwg & 7;
  const int xcd = orig & 7, choff = orig >> 3;
  const int wg = (xcd < rr2 ? xcd * (qq + 1) : rr2 * (qq + 1) + (xcd - rr2) * qq) + choff;
  const int m0 = (wg / gridDim.x) * 128;
  const int n0 = (wg % gridDim.x) * 64;

  const int w = tid >> 6, lane = tid & 63;       // 8 waves
  const int wr = w >> 1, wc = w & 1;             // wave tile 32x32: wr 0..3, wc 0..1
  const int fr = lane & 15, kg = lane >> 4;

  // staging: 3 passes x 64 rows (A rows 0..127, B rows 0..63); wave w covers
  // rows w*8..w*8+7 of each pass (LDS dest wave-uniform). Pre-swizzled source:
  // logical slot s = (lane&7) ^ ((row>>1)&7).
  const int lrow = lane >> 3, lslot = lane & 7;
  unsigned asrc0, asrc1, bsrc0;
  int aoff0, aoff1, boff0;
  {
    int r = w * 8 + lrow;                 // A pass 0: rows 0..63
    int s = lslot ^ ((r >> 1) & 7);
    int gr = m0 + r; if (gr >= M) gr = M - 1;
    asrc0 = (unsigned)gr * (unsigned)K + s * 8;
    aoff0 = (w * 8) * 64;
    r = 64 + w * 8 + lrow;                // A pass 1: rows 64..127
    s = lslot ^ ((r >> 1) & 7);
    gr = m0 + r; if (gr >= M) gr = M - 1;
    asrc1 = (unsigned)gr * (unsigned)K + s * 8;
    aoff1 = (64 + w * 8) * 64;
    r = w * 8 + lrow;                     // B pass: rows 0..63
    s = lslot ^ ((r >> 1) & 7);
    bsrc0 = (unsigned)(n0 + r) * (unsigned)K + s * 8;
    boff0 = (w * 8) * 64;
  }

  f32x4 acc[2][2] = {};

#define STAGE(buf, k0)                                                  \
  do {                                                                  \
    gload16(A + asrc0 + (k0), &Al[buf][aoff0]);                         \
    gload16(A + asrc1 + (k0), &Al[buf][aoff1]);                         \
    gload16(Bt + bsrc0 + (k0), &Bl[buf][boff0]);                        \
  } while (0)

#define COMPUTE(buf, kk)                                                \
  do {                                                                  \
    bf16x8 af[2], bfr[2];                                               \
    _Pragma("unroll")                                                   \
    for (int i = 0; i < 2; i++) {                                       \
      int ar = wr * 32 + i * 16 + fr;                                   \
      int p = ((kk) * 4 + kg) ^ ((ar >> 1) & 7);                        \
      af[i] = *(const bf16x8*)&Al[buf][ar * 64 + p * 8];                \
    }                                                                   \
    _Pragma("unroll")                                                   \
    for (int j = 0; j < 2; j++) {                                       \
      int br = wc * 32 + j * 16 + fr;                                   \
      int p = ((kk) * 4 + kg) ^ ((br >> 1) & 7);                        \
      bfr[j] = *(const bf16x8*)&Bl[buf][br * 64 + p * 8];               \
    }                                                                   \
    _Pragma("unroll")                                                   \
    for (int i = 0; i < 2; i++)                                         \
      _Pragma("unroll")                                                 \
      for (int j = 0; j < 2; j++)                                       \
        acc[i][j] = __builtin_amdgcn_mfma_f32_16x16x32_bf16(            \
            af[i], bfr[j], acc[i][j], 0, 0, 0);                         \
  } while (0)

  const int NT = K >> 6;
  STAGE(0, 0);
  __syncthreads();                 // buf0 visible
  int cur = 0;
  for (int t = 0; t < NT; ++t) {
    if (t + 1 < NT) STAGE(cur ^ 1, (t + 1) * 64);  // in flight over compute
    COMPUTE(cur, 0);
    COMPUTE(cur, 1);
    __syncthreads();               // drain stage; buf[cur] free
    cur ^= 1;
  }
#undef STAGE
#undef COMPUTE

  // epilogue: C/D layout col = lane&15 (n), row = (lane>>4)*4 + r (m)
  #pragma unroll
  for (int i = 0; i < 2; i++) {
    #pragma unroll
    for (int j = 0; j < 2; j++) {
      int n = n0 + wc * 32 + j * 16 + fr;
      #pragma unroll
      for (int r = 0; r < 4; r++) {
        int m = m0 + wr * 32 + i * 16 + kg * 4 + r;
        if (m >= M) continue;
        float u = acc[i][j][r];
        if (EPI == 0) {
          Cb[(size_t)m * N + n] = f2b(u);
        } else if (EPI == 1) {
          u += bias[n];
          Cf[(size_t)m * N + n] += u;
        } else if (EPI == 2) {
          u = fmaxf(u + bias[n], 0.f);
          Cb[(size_t)m * N + n] = f2b(u);
        } else {
          int tok = tok_base + (m % tpb);
          size_t orow = (size_t)(m / tpb) * SEQL + tok;
          u += bias[n] + g_pos[(size_t)tok * DM + n];
          Cf[orow * DM + n] = u;
        }
      }
    }
  }
}

// ---------------- MFMA flash attention ----------------
__global__ __launch_bounds__(256) void attn_flash() {
  constexpr int KS = 3 * DM;
  constexpr float scale = 0.03608439182435161f; // 768^-0.5
  __shared__ __align__(16) u16 Kl[64 * 64];
  __shared__ __align__(16) u16 Vt[64 * 64];
  const int tid = threadIdx.x;
  const int w = tid >> 6, lane = tid & 63;
  const int fr = lane & 15, kg = lane >> 4;
  const int qt = blockIdx.x, h = blockIdx.y, b = blockIdx.z;
  const int q0 = qt * 64 + w * 16;
  const size_t bbase = (size_t)b * SEQL * KS + h * HDIM;

  int qr = q0 + fr; if (qr >= SEQL) qr = SEQL - 1;
  const size_t qrow = bbase + (size_t)qr * KS;
  const bf16x8 bq0 = *(const bf16x8*)&g_qkvb[qrow + kg * 8];
  const bf16x8 bq1 = *(const bf16x8*)&g_qkvb[qrow + 32 + kg * 8];

  f32x4 oacc[4] = {};
  float m_run = -3e38f, l_run = 0.f;

  for (int kv0 = 0; kv0 < SEQL; kv0 += 64) {
    __syncthreads();
    { // stage K [64 keys][8 slots], phys = slot ^ ((row>>1)&7)
      int row = tid >> 2, s0 = tid & 3;
      int krow = kv0 + row; if (krow >= SEQL) krow = SEQL - 1;
      const size_t gk = bbase + DM + (size_t)krow * KS;
      int sw = (row >> 1) & 7;
      *(bf16x8*)&Kl[row * 64 + (s0 ^ sw) * 8]       = *(const bf16x8*)&g_qkvb[gk + s0 * 8];
      *(bf16x8*)&Kl[row * 64 + ((s0 + 4) ^ sw) * 8] = *(const bf16x8*)&g_qkvb[gk + (s0 + 4) * 8];
    }
    { // stage V^T [64 d][8 key-slots], phys = slot ^ ((d>>1)&7)
      int d0 = (tid & 15) * 4;
      #pragma unroll
      for (int kk = 0; kk < 4; kk++) {
        int kl = (tid >> 4) + kk * 16;
        int krow = kv0 + kl; if (krow >= SEQL) krow = SEQL - 1;
        ushort4 v4 = *(const ushort4*)&g_qkvb[bbase + 2 * DM + (size_t)krow * KS + d0];
        int slot = kl >> 3, e = kl & 7;
        u16 vv[4] = {v4.x, v4.y, v4.z, v4.w};
        #pragma unroll
        for (int i = 0; i < 4; i++) {
          int d = d0 + i;
          Vt[d * 64 + ((slot ^ ((d >> 1) & 7)) * 8) + e] = vv[i];
        }
      }
    }
    __syncthreads();

    f32x4 sacc[4] = {};
    #pragma unroll
    for (int f = 0; f < 4; f++) {
      int row = f * 16 + fr;
      int sw = (row >> 1) & 7;
      bf16x8 ka0 = *(const bf16x8*)&Kl[row * 64 + ((kg ^ sw) * 8)];
      bf16x8 ka1 = *(const bf16x8*)&Kl[row * 64 + (((kg + 4) ^ sw) * 8)];
      sacc[f] = __builtin_amdgcn_mfma_f32_16x16x32_bf16(ka0, bq0, sacc[f], 0, 0, 0);
      sacc[f] = __builtin_amdgcn_mfma_f32_16x16x32_bf16(ka1, bq1, sacc[f], 0, 0, 0);
    }

    float p[4][4];
    float tmax = -3e38f;
    #pragma unroll
    for (int f = 0; f < 4; f++) {
      int keyb = kv0 + f * 16 + kg * 4;
      #pragma unroll
      for (int r = 0; r < 4; r++) {
        float sv = (keyb + r < SEQL) ? sacc[f][r] * scale : -3e38f;
        p[f][r] = sv;
        tmax = fmaxf(tmax, sv);
      }
    }
    tmax = fmaxf(tmax, __shfl_xor(tmax, 16));
    tmax = fmaxf(tmax, __shfl_xor(tmax, 32));
    float m_new = fmaxf(m_run, tmax);
    float alpha = __expf(m_run - m_new);
    m_run = m_new;

    float lsum = 0.f;
    #pragma unroll
    for (int f = 0; f < 4; f++)
      #pragma unroll
      for (int r = 0; r < 4; r++) {
        float e = __expf(p[f][r] - m_new);
        p[f][r] = e;
        lsum += e;
      }
    lsum += __shfl_xor(lsum, 16);
    lsum += __shfl_xor(lsum, 32);
    l_run = l_run * alpha + lsum;

    #pragma unroll
    for (int r = 0; r < 4; r++) {
      float aq = __shfl(alpha, kg * 4 + r);
      #pragma unroll
      for (int dg = 0; dg < 4; dg++) oacc[dg][r] *= aq;
    }

    unsigned pk_[4][2];
    #pragma unroll
    for (int f = 0; f < 4; f++)
      #pragma unroll
      for (int rr = 0; rr < 2; rr++)
        pk_[f][rr] = (unsigned)f2b(p[f][2 * rr]) | ((unsigned)f2b(p[f][2 * rr + 1]) << 16);

    bf16x8 pa[2];
    const int srcA = fr + 16 * (2 * (kg & 1));
    const int srcB = srcA + 16;
    const bool fsel = (kg >> 1) != 0;
    #pragma unroll
    for (int s = 0; s < 2; s++) {
      unsigned w0a = __shfl(pk_[2 * s][0], srcA), w0b = __shfl(pk_[2 * s + 1][0], srcA);
      unsigned w1a = __shfl(pk_[2 * s][1], srcA), w1b = __shfl(pk_[2 * s + 1][1], srcA);
      unsigned w2a = __shfl(pk_[2 * s][0], srcB), w2b = __shfl(pk_[2 * s + 1][0], srcB);
      unsigned w3a = __shfl(pk_[2 * s][1], srcB), w3b = __shfl(pk_[2 * s + 1][1], srcB);
      union { unsigned u[4]; bf16x8 v; } cvt;
      cvt.u[0] = fsel ? w0b : w0a;
      cvt.u[1] = fsel ? w1b : w1a;
      cvt.u[2] = fsel ? w2b : w2a;
      cvt.u[3] = fsel ? w3b : w3a;
      pa[s] = cvt.v;
    }

    #pragma unroll
    for (int dg = 0; dg < 4; dg++) {
      int row = dg * 16 + fr;
      int sw = (row >> 1) & 7;
      bf16x8 bv0 = *(const bf16x8*)&Vt[row * 64 + ((kg ^ sw) * 8)];
      bf16x8 bv1 = *(const bf16x8*)&Vt[row * 64 + (((kg + 4) ^ sw) * 8)];
      oacc[dg] = __builtin_amdgcn_mfma_f32_16x16x32_bf16(pa[0], bv0, oacc[dg], 0, 0, 0);
      oacc[dg] = __builtin_amdgcn_mfma_f32_16x16x32_bf16(pa[1], bv1, oacc[dg], 0, 0, 0);
    }
  }

  float inv = 1.f / l_run;
  #pragma unroll
  for (int r = 0; r < 4; r++) {
    float iq = __shfl(inv, kg * 4 + r);
    int q = q0 + kg * 4 + r;
    if (q >= SEQL) continue;
    size_t orow = ((size_t)b * SEQL + q) * DM + h * HDIM;
    #pragma unroll
    for (int dg = 0; dg < 4; dg++)
      g_y[orow + dg * 16 + fr] = f2b(oacc[dg][r] * iq);
  }
}

// ---------------- final: LN(lnf) -> cls -> LN(hln) -> head (f32 out) --------
__global__ __launch_bounds__(256) void final_kernel(
    const float* __restrict__ lnf_g, const float* __restrict__ lnf_b,
    const float* __restrict__ hln_g, const float* __restrict__ hln_b,
    const float* __restrict__ head_w, const float* __restrict__ head_b,
    float* __restrict__ out) {
  __shared__ float tmp[4];
  __shared__ float red[4][7];
  int b = blockIdx.x, tid = threadIdx.x;
  const float* xr = g_x + (size_t)b * SEQL * DM;
  float v0[3];
  float s = 0.f;
  for (int i = 0; i < 3; i++) { v0[i] = xr[tid + i * 256]; s += v0[i]; }
  float mean = blk_sum256(s, tmp) * (1.f / 768.f);
  float vs = 0.f;
  for (int i = 0; i < 3; i++) { float dd = v0[i] - mean; vs += dd * dd; }
  float var = blk_sum256(vs, tmp) * (1.f / 768.f);
  float rstd = rsqrtf(var + 1e-5f);
  float t1v[3];
  s = 0.f;
  for (int i = 0; i < 3; i++) {
    int d = tid + i * 256;
    t1v[i] = (v0[i] - mean) * rstd * lnf_g[d] + lnf_b[d];
    s += t1v[i];
  }
  float mean2 = blk_sum256(s, tmp) * (1.f / 768.f);
  vs = 0.f;
  for (int i = 0; i < 3; i++) { float dd = t1v[i] - mean2; vs += dd * dd; }
  float var2 = blk_sum256(vs, tmp) * (1.f / 768.f);
  float rstd2 = rsqrtf(var2 + 1e-5f);
  float po[7] = {};
  for (int i = 0; i < 3; i++) {
    int d = tid + i * 256;
    float t2 = (t1v[i] - mean2) * rstd2 * hln_g[d] + hln_b[d];
    for (int oo = 0; oo < 7; oo++) po[oo] += t2 * head_w[d * 7 + oo];
  }
  #pragma unroll
  for (int oo = 0; oo < 7; oo++) {
    #pragma unroll
    for (int off = 32; off; off >>= 1) po[oo] += __shfl_xor(po[oo], off);
  }
  if ((tid & 63) == 0) {
    int ww = tid >> 6;
    for (int oo = 0; oo < 7; oo++) red[ww][oo] = po[oo];
  }
  __syncthreads();
  if (tid < 7)
    out[b * 7 + tid] = red[0][tid] + red[1][tid] + red[2][tid] + red[3][tid] + head_b[tid];
}

// ---------------- host launch ----------------
extern "C" void kernel_launch(void* const* d_in, const int* in_sizes, int n_in,
                              void* d_out, int out_size, void* d_ws, size_t ws_size,
                              hipStream_t stream) {
  const float* images    = (const float*)d_in[0];
  const float* goal_imgs = (const float*)d_in[1];
  const float* pose      = (const float*)d_in[2];
  const int*   goals_txt = (const int*)  d_in[3];
  const float* obs_w     = (const float*)d_in[4];
  const float* obs_b     = (const float*)d_in[5];
  const float* goal_w    = (const float*)d_in[6];
  const float* goal_b    = (const float*)d_in[7];
  const float* tok_emb   = (const float*)d_in[8];
  const float* pose_w1   = (const float*)d_in[9];
  const float* pose_b1   = (const float*)d_in[10];
  const float* pose_w2   = (const float*)d_in[11];
  const float* pose_b2   = (const float*)d_in[12];
  const float* cls_tok   = (const float*)d_in[13];
  const float* wq        = (const float*)d_in[14];
  const float* wk        = (const float*)d_in[15];
  const float* wv        = (const float*)d_in[16];
  const float* proj_w    = (const float*)d_in[17];
  const float* proj_b    = (const float*)d_in[18];
  const float* ln1_g     = (const float*)d_in[19];
  const float* ln1_b     = (const float*)d_in[20];
  const float* ln2_g     = (const float*)d_in[21];
  const float* ln2_b     = (const float*)d_in[22];
  const float* ff_w1     = (const float*)d_in[23];
  const float* ff_b1     = (const float*)d_in[24];
  const float* ff_w2     = (const float*)d_in[25];
  const float* ff_b2     = (const float*)d_in[26];
  const float* lnf_g     = (const float*)d_in[27];
  const float* lnf_b     = (const float*)d_in[28];
  const float* hln_g     = (const float*)d_in[29];
  const float* hln_b     = (const float*)d_in[30];
  const float* head_w    = (const float*)d_in[31];
  const float* head_b    = (const float*)d_in[32];
  (void)d_ws; (void)ws_size; (void)in_sizes; (void)n_in; (void)out_size;

  u16* wqkvT; u16* wpT; u16* w1T; u16* w2T; u16* obsT; u16* goalT;
  hipGetSymbolAddress((void**)&wqkvT, HIP_SYMBOL(g_wqkvT));
  hipGetSymbolAddress((void**)&wpT,   HIP_SYMBOL(g_wpT));
  hipGetSymbolAddress((void**)&w1T,   HIP_SYMBOL(g_w1T));
  hipGetSymbolAddress((void**)&w2T,   HIP_SYMBOL(g_w2T));
  hipGetSymbolAddress((void**)&obsT,  HIP_SYMBOL(g_obsT));
  hipGetSymbolAddress((void**)&goalT, HIP_SYMBOL(g_goalT));
  u16* qkvb; u16* yb; u16* hid; u16* pobs; u16* pgoal; float* xb;
  hipGetSymbolAddress((void**)&qkvb, HIP_SYMBOL(g_qkvb));
  hipGetSymbolAddress((void**)&yb,   HIP_SYMBOL(g_y));
  hipGetSymbolAddress((void**)&hid,  HIP_SYMBOL(g_hid));
  hipGetSymbolAddress((void**)&pobs, HIP_SYMBOL(g_pobs));
  hipGetSymbolAddress((void**)&pgoal,HIP_SYMBOL(g_pgoal));
  hipGetSymbolAddress((void**)&xb,   HIP_SYMBOL(g_x));

  const size_t WS = (size_t)DM * DM;
  const size_t FS = (size_t)DM * FF;

  // weight convert+transpose
  convT_kernel<<<dim3(24, 24, 12), 256, 0, stream>>>(wq,     wqkvT,          DM, DM, WS, 3 * WS);
  convT_kernel<<<dim3(24, 24, 12), 256, 0, stream>>>(wk,     wqkvT + WS,     DM, DM, WS, 3 * WS);
  convT_kernel<<<dim3(24, 24, 12), 256, 0, stream>>>(wv,     wqkvT + 2 * WS, DM, DM, WS, 3 * WS);
  convT_kernel<<<dim3(24, 24, 12), 256, 0, stream>>>(proj_w, wpT,            DM, DM, WS, WS);
  convT_kernel<<<dim3(96, 24, 12), 256, 0, stream>>>(ff_w1,  w1T,            DM, FF, FS, FS);
  convT_kernel<<<dim3(24, 96, 12), 256, 0, stream>>>(ff_w2,  w2T,            FF, DM, FS, FS);
  convT_kernel<<<dim3(24, 24, 1),  256, 0, stream>>>(obs_w,  obsT,           DM, DM, 0, 0);
  convT_kernel<<<dim3(24, 24, 1),  256, 0, stream>>>(goal_w, goalT,          DM, DM, 0, 0);

  pos_kernel<<<SEQL, 256, 0, stream>>>();
  patchify_stacked_kernel<<<NB * 392, 256, 0, stream>>>(images);
  patchify3_kernel<<<NB * 196, 256, 0, stream>>>(goal_imgs);
  pose1_kernel<<<NB, 256, 0, stream>>>(pose, pose_w1, pose_b1);
  pose2_kernel<<<NB * 12, 256, 0, stream>>>(pose_w2, pose_b2);
  embed_misc_kernel<<<NB * 79, 256, 0, stream>>>(cls_tok, tok_emb, goals_txt);

  gemm_bf16<3><<<dim3(12, 25), 512, 0, stream>>>(
      pobs, obsT, obs_b, xb, nullptr, NB * 392, DM, DM, 392, 2);
  gemm_bf16<3><<<dim3(12, 13), 512, 0, stream>>>(
      pgoal, goalT, goal_b, xb, nullptr, NB * 196, DM, DM, 196, 471);

  for (int l = 0; l < 12; l++) {
    ln_kernel<<<ROWS / 4, 256, 0, stream>>>(ln1_g + l * DM, ln1_b + l * DM);
    gemm_bf16<0><<<dim3(36, 42), 512, 0, stream>>>(
        yb, wqkvT + (size_t)l * 3 * WS, nullptr, nullptr, qkvb, ROWS, 3 * DM, DM, 0, 0);
    attn_flash<<<dim3(11, NHEAD, NB), 256, 0, stream>>>();
    gemm_bf16<1><<<dim3(12, 42), 512, 0, stream>>>(
        yb, wpT + (size_t)l * WS, proj_b + l * DM, xb, nullptr, ROWS, DM, DM, 0, 0);
    ln_kernel<<<ROWS / 4, 256, 0, stream>>>(ln2_g + l * DM, ln2_b + l * DM);
    gemm_bf16<2><<<dim3(48, 42), 512, 0, stream>>>(
        yb, w1T + (size_t)l * FS, ff_b1 + l * FF, nullptr, hid, ROWS, FF, DM, 0, 0);
    gemm_bf16<1><<<dim3(12, 42), 512, 0, stream>>>(
        hid, w2T + (size_t)l * FS, ff_b2 + l * DM, xb, nullptr, ROWS, DM, FF, 0, 0);
  }

  final_kernel<<<NB, 256, 0, stream>>>(lnf_g, lnf_b, hln_g, hln_b, head_w, head_b,
                                       (float*)d_out);
}